// Round 2
// baseline (287.462 us; speedup 1.0000x reference)
//
#include <hip/hip_runtime.h>
#include <stdint.h>

#define Bb 8
#define PREK 1024
#define POSTK 300
#define NBIN 120            // scores 9..127+ -> bin = s-9
#define NCHUNK 512          // chunks of 256 candidates per batch
#define MAXG 16             // 16*64 = up to 1024 boxes per class (general)

__device__ __forceinline__ float clampb(float v){ return fminf(fmaxf(v, 0.0f), 1024.0f); }

// K1: best score + first-argmax per anchor cell (int4 vectorized), packed u16 [(s+128)<<8|lab],
//     layout sc16[b][a][h*128+w]; per-32w-chunk histogram -> chist[(b*512+ci)*120+bin]
__global__ void __launch_bounds__(256) k1_scores(const int* __restrict__ data,
                                                 unsigned short* __restrict__ sc16,
                                                 int* __restrict__ chist){
    int blk = blockIdx.x;                 // 8*128: (b, h)
    int b = blk >> 7, h = blk & 127;
    int tid = threadIdx.x;
    int a = tid >> 5, wg = tid & 31;      // wg: group of 4 w
    int w = wg << 2;
    const int* p = data + (((size_t)(b*96 + a*12 + 4)) << 14) + (h << 7) + w;
    int4 m = *(const int4*)p;
    int4 lb = make_int4(0,0,0,0);
#pragma unroll
    for (int c = 1; c < 8; ++c){
        int4 v = *(const int4*)(p + ((size_t)c << 14));
        if (v.x > m.x){ m.x = v.x; lb.x = c; }
        if (v.y > m.y){ m.y = v.y; lb.y = c; }
        if (v.z > m.z){ m.z = v.z; lb.z = c; }
        if (v.w > m.w){ m.w = v.w; lb.w = c; }
    }
    ushort4 st;
    st.x = (unsigned short)(((m.x + 128) << 8) | lb.x);
    st.y = (unsigned short)(((m.y + 128) << 8) | lb.y);
    st.z = (unsigned short)(((m.z + 128) << 8) | lb.z);
    st.w = (unsigned short)(((m.w + 128) << 8) | lb.w);
    *(ushort4*)(sc16 + (((size_t)(b*8 + a)) << 14) + (h << 7) + w) = st;

    __shared__ int hist[4][NBIN];
    for (int i = tid; i < 4*NBIN; i += 256) ((int*)hist)[i] = 0;
    __syncthreads();
    int q = wg >> 3;                       // chunk-within-row (32 w per chunk)
    if (m.x >= 9) atomicAdd(&hist[q][m.x-9], 1);
    if (m.y >= 9) atomicAdd(&hist[q][m.y-9], 1);
    if (m.z >= 9) atomicAdd(&hist[q][m.z-9], 1);
    if (m.w >= 9) atomicAdd(&hist[q][m.w-9], 1);
    __syncthreads();
    int* cbase = chist + ((size_t)(b*NCHUNK + h*4)) * NBIN;
    for (int i = tid; i < 4*NBIN; i += 256) cbase[i] = ((int*)hist)[i];
}

// K2: per batch: global hist (coalesced+LDS atomics), parallel suffix -> gt/T, init topidx,
//     then parallel exclusive scan over 512 chunks for each bin >= T
__global__ void __launch_bounds__(256) k2_select(int* __restrict__ chist, int* __restrict__ gt,
                                                 int* __restrict__ Tb_, int* __restrict__ topidx){
    int b = blockIdx.x, tid = threadIdx.x;
    __shared__ int hs[NBIN];
    __shared__ int suf[128];
    __shared__ int Tsh;
    __shared__ int sb[512];
    for (int i = tid; i < NBIN; i += 256) hs[i] = 0;
    if (tid == 0) Tsh = -1;
    __syncthreads();
    const int* cb = chist + (size_t)b * NCHUNK * NBIN;
    for (int idx = tid; idx < NCHUNK*NBIN; idx += 256){
        int v = cb[idx];
        if (v) atomicAdd(&hs[idx % NBIN], v);
    }
    __syncthreads();
    if (tid < 128) suf[tid] = (tid < NBIN) ? hs[tid] : 0;
    __syncthreads();
    for (int off = 1; off < 128; off <<= 1){
        int v = 0;
        if (tid < 128 && tid + off < 128) v = suf[tid + off];
        __syncthreads();
        if (tid < 128) suf[tid] += v;
        __syncthreads();
    }
    if (tid < NBIN){
        gt[b*128 + tid] = suf[tid] - hs[tid];          // strictly-greater count
        if (suf[tid] >= PREK) atomicMax(&Tsh, tid);    // suffix-inclusive >= K
    }
    __syncthreads();
    int T = Tsh > 0 ? Tsh : 0;
    if (tid == 0) Tb_[b] = T;
    for (int k = tid; k < PREK; k += 256) topidx[b*PREK + k] = -1;
    // exclusive scan over chunks for active bins
    int i0 = tid, i1 = tid + 256;
    for (int bin = T; bin < NBIN; ++bin){
        int* basep = chist + (size_t)(b*NCHUNK) * NBIN + bin;
        int v0 = basep[(size_t)i0 * NBIN], v1 = basep[(size_t)i1 * NBIN];
        sb[i0] = v0; sb[i1] = v1;
        __syncthreads();
        for (int off = 1; off < 512; off <<= 1){
            int a0 = (i0 >= off) ? sb[i0 - off] : 0;
            int a1 = (i1 >= off) ? sb[i1 - off] : 0;
            __syncthreads();
            sb[i0] += a0; sb[i1] += a1;
            __syncthreads();
        }
        basep[(size_t)i0 * NBIN] = sb[i0] - v0;
        basep[(size_t)i1 * NBIN] = sb[i1] - v1;
        __syncthreads();
    }
}

// K3: stable rank via ballot eq-count + cross-wave hist; scatter topidx/topps
__global__ void __launch_bounds__(256) k3_rank(const unsigned short* __restrict__ sc16,
                                               const int* __restrict__ chist,
                                               const int* __restrict__ gt, const int* __restrict__ Tb_,
                                               int* __restrict__ topidx, int* __restrict__ topps){
    int blk = blockIdx.x;                // 8*512: (b, ci)
    int b = blk >> 9, ci = blk & 511;
    int tid = threadIdx.x;
    int h = ci >> 2, w0 = (ci & 3) << 5;
    __shared__ unsigned short sc[256];
    __shared__ int wcnt[4][NBIN];
    if (tid < 64){
        int a = tid & 7, wq = tid >> 3;
        ushort4 v = *(const ushort4*)(sc16 + (((size_t)(b*8 + a)) << 14) + (h << 7) + w0 + (wq << 2));
        sc[(wq*4 + 0)*8 + a] = v.x;
        sc[(wq*4 + 1)*8 + a] = v.y;
        sc[(wq*4 + 2)*8 + a] = v.z;
        sc[(wq*4 + 3)*8 + a] = v.w;
    }
    for (int i = tid; i < 4*NBIN; i += 256) ((int*)wcnt)[i] = 0;
    int T = Tb_[b];
    __syncthreads();
    unsigned short v = sc[tid];
    int s = (int)(v >> 8) - 128;
    int bin = s - 9;
    bool qual = (bin >= T);
    int wv = tid >> 6, lane = tid & 63;
    if (qual) atomicAdd(&wcnt[wv][bin], 1);
    __syncthreads();
    unsigned long long anyq = __ballot(qual);
    int myeq = 0;
    if (anyq){
        unsigned long long low = (1ull << lane) - 1ull;
        for (int vb = T; vb < NBIN; ++vb){
            unsigned long long bal = __ballot(qual && bin == vb);
            if (!bal) continue;
            if (qual && bin == vb) myeq = __popcll(bal & low);
        }
    }
    if (!qual) return;
    int cross = 0;
    for (int w2 = 0; w2 < wv; ++w2) cross += wcnt[w2][bin];
    int rank = gt[b*128 + bin] + chist[((size_t)(b*NCHUNK) + ci)*NBIN + bin] + cross + myeq;
    if (rank < PREK){
        topidx[b*PREK + rank] = ci*256 + tid;
        topps[b*PREK + rank] = (int)v;
    }
}

// K4: per batch (1024 thr): decode selected boxes bit-exact, stable per-class partition via ballots,
//     write class-compacted offset-boxes/areas/rank/class + per-rank score
__global__ void __launch_bounds__(1024) k4_decode(const int* __restrict__ data,
                                                  const float* __restrict__ anchors,
                                                  const int* __restrict__ etab,
                                                  const int* __restrict__ topidx, const int* __restrict__ topps,
                                                  float4* __restrict__ cbox, float* __restrict__ car,
                                                  unsigned short* __restrict__ ckl, unsigned char* __restrict__ ccls,
                                                  int* __restrict__ ccnt, int* __restrict__ cbase,
                                                  float* __restrict__ scf){
    int b = blockIdx.x, k = threadIdx.x;
    int lane = k & 63, wv = k >> 6;
    int pp = topidx[b*PREK + k];
    float x1=0.f, y1=0.f, x2=0.f, y2=0.f, sval=0.f;
    int lc = -1;
    if (pp >= 0){
        int ps = topps[b*PREK + k];
        int s = (ps >> 8) - 128; lc = ps & 255;
        sval = __fmul_rn((float)s, 0.0625f);
        int a = pp & 7, h = pp >> 10, w = (pp >> 3) & 127;
        const int* p = data + (((size_t)(b*96 + a*12)) << 14) + (h << 7) + w;
        int d0 = p[0], d1 = p[1 << 14], d2 = p[2 << 14], d3 = p[3 << 14];
        float4 an = ((const float4*)anchors)[pp];
        float cx = __fmul_rn(__fadd_rn(an.x, an.z), 0.5f);
        float cy = __fmul_rn(__fadd_rn(an.y, an.w), 0.5f);
        float wx = __fsub_rn(an.z, an.x), wy = __fsub_rn(an.w, an.y);
        float dx = __fmul_rn((float)d0, 0.0625f), dy = __fmul_rn((float)d1, 0.0625f);
        float ex = __fmul_rn((float)etab[d2 + 128], 0.0625f);
        float ey = __fmul_rn((float)etab[d3 + 128], 0.0625f);
        float pcx = __fadd_rn(cx, __fmul_rn(dx, wx));
        float pcy = __fadd_rn(cy, __fmul_rn(dy, wy));
        float hx = __fmul_rn(__fmul_rn(wx, ex), 0.5f);
        float hy = __fmul_rn(__fmul_rn(wy, ey), 0.5f);
        x1 = clampb(__fsub_rn(pcx, hx)); y1 = clampb(__fsub_rn(pcy, hy));
        x2 = clampb(__fadd_rn(pcx, hx)); y2 = clampb(__fadd_rn(pcy, hy));
    }
    scf[b*PREK + k] = sval;
    __shared__ int wq[16][8];
    __shared__ int cbs[8], ccn[8];
    int win = 0;
#pragma unroll
    for (int c = 0; c < 8; ++c){
        unsigned long long bal = __ballot(lc == c);
        if (lane == 0) wq[wv][c] = __popcll(bal);
        if (lc == c) win = __popcll(bal & ((1ull << lane) - 1ull));
    }
    __syncthreads();
    if (k < 8){
        int run = 0;
        for (int w2 = 0; w2 < 16; ++w2){ int t = wq[w2][k]; wq[w2][k] = run; run += t; }
        ccn[k] = run;
    }
    __syncthreads();
    if (k == 0){
        int run = 0;
        for (int c = 0; c < 8; ++c){ cbs[c] = run; run += ccn[c]; }
    }
    __syncthreads();
    if (k < 8){ ccnt[b*8 + k] = ccn[k]; cbase[b*8 + k] = cbs[k]; }
    if (lc >= 0){
        int p = cbs[lc] + wq[wv][lc] + win;
        float off = (float)(lc << 12);
        float ox1 = __fadd_rn(x1, off), oy1 = __fadd_rn(y1, off);
        float ox2 = __fadd_rn(x2, off), oy2 = __fadd_rn(y2, off);
        cbox[b*PREK + p] = make_float4(ox1, oy1, ox2, oy2);
        car[b*PREK + p]  = __fmul_rn(__fsub_rn(ox2, ox1), __fsub_rn(oy2, oy1));
        ckl[b*PREK + p]  = (unsigned short)k;
        ccls[b*PREK + p] = (unsigned char)lc;
    }
}

// K5: per batch (512 thr = 8 waves, one class each): register-cached greedy NMS with shfl'd
//     suppression bitmask, then in-block ballot compaction to the 300 outputs
__global__ void __launch_bounds__(512) k5_nms_out(const float4* __restrict__ cbox, const float* __restrict__ car,
                                                  const unsigned short* __restrict__ ckl,
                                                  const unsigned char* __restrict__ ccls,
                                                  const int* __restrict__ ccnt, const int* __restrict__ cbase,
                                                  const float* __restrict__ scf, float* __restrict__ out){
    int b = blockIdx.x, tid = threadIdx.x, lane = tid & 63, wv = tid >> 6;
    __shared__ float X1[1024], Y1[1024], X2[1024], Y2[1024], AR[1024];
    __shared__ unsigned short CKL[1024];
    __shared__ unsigned char CCLS[1024];
    __shared__ short RS[1024];
    __shared__ unsigned char KEEP[1024];
    __shared__ int ccn[8], cbs[8];
    __shared__ int wcn[8];
    __shared__ int pbase;
    if (tid < 8){ ccn[tid] = ccnt[b*8 + tid]; cbs[tid] = cbase[b*8 + tid]; }
    if (tid == 0) pbase = 0;
    for (int p = tid; p < 1024; p += 512){ RS[p] = -1; KEEP[p] = 0; }
    __syncthreads();
    int total = cbs[7] + ccn[7];
    for (int p = tid; p < 1024; p += 512){
        if (p < total){
            float4 bb = cbox[b*PREK + p];
            X1[p] = bb.x; Y1[p] = bb.y; X2[p] = bb.z; Y2[p] = bb.w;
            AR[p] = car[b*PREK + p];
            unsigned short kk = ckl[b*PREK + p];
            CKL[p] = kk; CCLS[p] = ccls[b*PREK + p];
            RS[kk] = (short)p;
        }
    }
    __syncthreads();
    int M = ccn[wv], base = cbs[wv];
    if (M > 0){
        float jx1[MAXG], jy1[MAXG], jx2[MAXG], jy2[MAXG], ja[MAXG];
#pragma unroll
        for (int g = 0; g < MAXG; ++g){
            int idx = g*64 + lane;
            int ad = base + ((idx < M) ? idx : 0);
            jx1[g] = X1[ad]; jy1[g] = Y1[ad]; jx2[g] = X2[ad]; jy2[g] = Y2[ad]; ja[g] = AR[ad];
        }
        unsigned int sup = 0;
        float nx1 = X1[base], ny1 = Y1[base], nx2 = X2[base], ny2 = Y2[base], na = AR[base];
        for (int i = 0; i < M; ++i){
            float xi1 = nx1, yi1 = ny1, xi2 = nx2, yi2 = ny2, ai = na;
            int ip = i + 1;
            int ad = base + ((ip < M) ? ip : 0);
            nx1 = X1[ad]; ny1 = Y1[ad]; nx2 = X2[ad]; ny2 = Y2[ad]; na = AR[ad];   // prefetch
            unsigned int srow = (unsigned int)__shfl((int)sup, i & 63);
            if (!((srow >> (i >> 6)) & 1u)){
#pragma unroll
                for (int g = 0; g < MAXG; ++g){
                    int jj = g*64 + lane;
                    if (jj < M && jj > i && !((sup >> g) & 1u)){
                        float wx = fmaxf(__fsub_rn(fminf(xi2, jx2[g]), fmaxf(xi1, jx1[g])), 0.0f);
                        float wy = fmaxf(__fsub_rn(fminf(yi2, jy2[g]), fmaxf(yi1, jy1[g])), 0.0f);
                        float inter = __fmul_rn(wx, wy);
                        float den = __fadd_rn(__fsub_rn(__fadd_rn(ai, ja[g]), inter), 1e-9f);
                        if (__fdiv_rn(inter, den) > 0.5f) sup |= (1u << g);
                    }
                }
            }
        }
#pragma unroll
        for (int g = 0; g < MAXG; ++g){
            int idx = g*64 + lane;
            if (idx < M) KEEP[CKL[base + idx]] = (unsigned char)(((sup >> g) & 1u) ^ 1u);
        }
    }
    __syncthreads();
    float* boxes  = out;
    float* scores = out + Bb*POSTK*4;
    float* labs   = out + Bb*POSTK*5;
    for (int pass = 0; pass < 2; ++pass){
        int e = pass*512 + tid;
        int kp = KEEP[e];
        unsigned long long bal = __ballot(kp != 0);
        if (lane == 0) wcn[wv] = __popcll(bal);
        __syncthreads();
        if (tid == 0){
            int r = pbase;
            for (int w2 = 0; w2 < 8; ++w2){ int t = wcn[w2]; wcn[w2] = r; r += t; }
            pbase = r;
        }
        __syncthreads();
        int pos = wcn[wv] + __popcll(bal & ((1ull << lane) - 1ull));
        if (kp && pos < POSTK){
            int p = RS[e];
            int c = CCLS[p];
            float off = (float)(c << 12);
            int o = (b*POSTK + pos)*4;
            boxes[o+0] = __fsub_rn(X1[p], off);
            boxes[o+1] = __fsub_rn(Y1[p], off);
            boxes[o+2] = __fsub_rn(X2[p], off);
            boxes[o+3] = __fsub_rn(Y2[p], off);
            scores[b*POSTK + pos] = scf[b*PREK + e];
            labs[b*POSTK + pos] = (float)c;
        }
        __syncthreads();
    }
    int tot = pbase < POSTK ? pbase : POSTK;
    for (int sl = tot + tid; sl < POSTK; sl += 512){
        int o = (b*POSTK + sl)*4;
        boxes[o+0] = 0.f; boxes[o+1] = 0.f; boxes[o+2] = 0.f; boxes[o+3] = 0.f;
        scores[b*POSTK + sl] = 0.f;
        labs[b*POSTK + sl] = -1.0f;
    }
}

extern "C" void kernel_launch(void* const* d_in, const int* in_sizes, int n_in,
                              void* d_out, int out_size, void* d_ws, size_t ws_size,
                              hipStream_t stream) {
    const int*   data    = (const int*)d_in[0];
    const float* anchors = (const float*)d_in[1];
    const int*   etab    = (const int*)d_in[2];
    float* out = (float*)d_out;

    char* ws = (char*)d_ws;
    size_t off = 0;
    auto alloc = [&](size_t bytes)->char*{ char* p = ws + off; off += (bytes + 255) & ~(size_t)255; return p; };
    unsigned short* sc16 = (unsigned short*)alloc((size_t)Bb*8*16384*2);      // 2 MB
    int* chist           = (int*)alloc((size_t)Bb*NCHUNK*NBIN*4);             // 1.9 MB
    int* gt              = (int*)alloc((size_t)Bb*128*4);
    int* Tb_             = (int*)alloc((size_t)Bb*4);
    int* topidx          = (int*)alloc((size_t)Bb*PREK*4);
    int* topps           = (int*)alloc((size_t)Bb*PREK*4);
    float4* cbox         = (float4*)alloc((size_t)Bb*PREK*16);
    float* car           = (float*)alloc((size_t)Bb*PREK*4);
    unsigned short* ckl  = (unsigned short*)alloc((size_t)Bb*PREK*2);
    unsigned char* ccls  = (unsigned char*)alloc((size_t)Bb*PREK);
    int* ccnt            = (int*)alloc((size_t)Bb*8*4);
    int* cbase           = (int*)alloc((size_t)Bb*8*4);
    float* scf           = (float*)alloc((size_t)Bb*PREK*4);
    (void)ws_size; (void)in_sizes; (void)n_in; (void)out_size;

    k1_scores<<<Bb*128, 256, 0, stream>>>(data, sc16, chist);
    k2_select<<<Bb, 256, 0, stream>>>(chist, gt, Tb_, topidx);
    k3_rank<<<Bb*NCHUNK, 256, 0, stream>>>(sc16, chist, gt, Tb_, topidx, topps);
    k4_decode<<<Bb, 1024, 0, stream>>>(data, anchors, etab, topidx, topps,
                                       cbox, car, ckl, ccls, ccnt, cbase, scf);
    k5_nms_out<<<Bb, 512, 0, stream>>>(cbox, car, ckl, ccls, ccnt, cbase, scf, out);
}

// Round 5
// 178.303 us; speedup vs baseline: 1.6122x; 1.6122x over previous
//
#include <hip/hip_runtime.h>
#include <stdint.h>

#define Bb 8
#define PREK 1024
#define POSTK 300
#define NBIN 120            // scores 9..127 -> bin = s-9
#define NCHUNK 512          // 256-candidate chunks per batch

__device__ __forceinline__ float clampb(float v){ return fminf(fmaxf(v, 0.0f), 1024.0f); }

// K1: best score + first-argmax per anchor (int4 vectorized), packed u16 [(s+128)<<8|lab]
//     layout sc16[b][a][h*128+w]; per-32w-chunk histogram -> chist[(b*512+ci)*120+bin]
__global__ void __launch_bounds__(256) k1_scores(const int* __restrict__ data,
                                                 unsigned short* __restrict__ sc16,
                                                 int* __restrict__ chist){
    int blk = blockIdx.x;                 // 8*128: (b, h)
    int b = blk >> 7, h = blk & 127;
    int tid = threadIdx.x;
    int a = tid >> 5, wg = tid & 31;
    int w = wg << 2;
    const int* p = data + (((size_t)(b*96 + a*12 + 4)) << 14) + (h << 7) + w;
    int4 m = *(const int4*)p;
    int4 lb = make_int4(0,0,0,0);
#pragma unroll
    for (int c = 1; c < 8; ++c){
        int4 v = *(const int4*)(p + ((size_t)c << 14));
        if (v.x > m.x){ m.x = v.x; lb.x = c; }
        if (v.y > m.y){ m.y = v.y; lb.y = c; }
        if (v.z > m.z){ m.z = v.z; lb.z = c; }
        if (v.w > m.w){ m.w = v.w; lb.w = c; }
    }
    ushort4 st;
    st.x = (unsigned short)(((m.x + 128) << 8) | lb.x);
    st.y = (unsigned short)(((m.y + 128) << 8) | lb.y);
    st.z = (unsigned short)(((m.z + 128) << 8) | lb.z);
    st.w = (unsigned short)(((m.w + 128) << 8) | lb.w);
    *(ushort4*)(sc16 + (((size_t)(b*8 + a)) << 14) + (h << 7) + w) = st;

    __shared__ int hist[4][NBIN];
    for (int i = tid; i < 4*NBIN; i += 256) ((int*)hist)[i] = 0;
    __syncthreads();
    int q = wg >> 3;
    if (m.x >= 9) atomicAdd(&hist[q][m.x-9], 1);
    if (m.y >= 9) atomicAdd(&hist[q][m.y-9], 1);
    if (m.z >= 9) atomicAdd(&hist[q][m.z-9], 1);
    if (m.w >= 9) atomicAdd(&hist[q][m.w-9], 1);
    __syncthreads();
    int* cb = chist + ((size_t)(b*NCHUNK + h*4)) * NBIN;
    for (int i = tid; i < 4*NBIN; i += 256) cb[i] = ((int*)hist)[i];
}

// K2: per batch: column-sum global hist (coalesced, no atomics), suffix -> gt/T,
//     init dmeta, then exclusive chunk-scan for bins >= T
__global__ void __launch_bounds__(256) k2_select(int* __restrict__ chist, int* __restrict__ gt,
                                                 int* __restrict__ Tb_, int* __restrict__ dmeta){
    int b = blockIdx.x, tid = threadIdx.x;
    __shared__ int hs2[2][NBIN];
    __shared__ int suf[128];
    __shared__ int Tsh;
    __shared__ int sb[512];
    if (tid == 0) Tsh = -1;
    int half = tid >> 7, bin = tid & 127;
    const int* cb = chist + (size_t)b * NCHUNK * NBIN;
    if (bin < NBIN){
        int s = 0;
        const int* p2 = cb + (size_t)half*256*NBIN + bin;
#pragma unroll 8
        for (int ch = 0; ch < 256; ++ch) s += p2[(size_t)ch * NBIN];
        hs2[half][bin] = s;
    }
    __syncthreads();
    int hbin = 0;
    if (tid < 128){
        hbin = (tid < NBIN) ? hs2[0][tid] + hs2[1][tid] : 0;
        suf[tid] = hbin;
    }
    __syncthreads();
    for (int off = 1; off < 128; off <<= 1){
        int v = 0;
        if (tid < 128 && tid + off < 128) v = suf[tid + off];
        __syncthreads();
        if (tid < 128) suf[tid] += v;
        __syncthreads();
    }
    if (tid < NBIN){
        gt[b*128 + tid] = suf[tid] - hbin;
        if (suf[tid] >= PREK) atomicMax(&Tsh, tid);
    }
    __syncthreads();
    int T = Tsh > 0 ? Tsh : 0;
    if (tid == 0) Tb_[b] = T;
    for (int k = tid; k < PREK; k += 256) dmeta[b*PREK + k] = -1;
    int i0 = tid, i1 = tid + 256;
    for (int abin = T; abin < NBIN; ++abin){
        int* basep = chist + (size_t)(b*NCHUNK) * NBIN + abin;
        int v0 = basep[(size_t)i0 * NBIN], v1 = basep[(size_t)i1 * NBIN];
        sb[i0] = v0; sb[i1] = v1;
        __syncthreads();
        for (int off = 1; off < 512; off <<= 1){
            int a0 = (i0 >= off) ? sb[i0 - off] : 0;
            int a1 = (i1 >= off) ? sb[i1 - off] : 0;
            __syncthreads();
            sb[i0] += a0; sb[i1] += a1;
            __syncthreads();
        }
        basep[(size_t)i0 * NBIN] = sb[i0] - v0;
        basep[(size_t)i1 * NBIN] = sb[i1] - v1;
        __syncthreads();
    }
}

// K3: stable rank via ballots + cross-wave hist; ranked candidates decode their box
//     bit-exact and scatter dbox/dmeta by rank
__global__ void __launch_bounds__(256) k3_rank(const unsigned short* __restrict__ sc16,
                                               const int* __restrict__ chist,
                                               const int* __restrict__ gt, const int* __restrict__ Tb_,
                                               const int* __restrict__ data,
                                               const float* __restrict__ anchors,
                                               const int* __restrict__ etab,
                                               float4* __restrict__ dbox, int* __restrict__ dmeta){
    int blk = blockIdx.x;                // 8*512: (b, ci)
    int b = blk >> 9, ci = blk & 511;
    int tid = threadIdx.x;
    int h = ci >> 2, w0 = (ci & 3) << 5;
    __shared__ unsigned short sc[256];
    __shared__ int wcnt[4][NBIN];
    if (tid < 64){
        int a = tid & 7, wq = tid >> 3;
        ushort4 v4 = *(const ushort4*)(sc16 + (((size_t)(b*8 + a)) << 14) + (h << 7) + w0 + (wq << 2));
        sc[(wq*4 + 0)*8 + a] = v4.x;
        sc[(wq*4 + 1)*8 + a] = v4.y;
        sc[(wq*4 + 2)*8 + a] = v4.z;
        sc[(wq*4 + 3)*8 + a] = v4.w;
    }
    for (int i = tid; i < 4*NBIN; i += 256) ((int*)wcnt)[i] = 0;
    int T = Tb_[b];
    __syncthreads();
    unsigned short v = sc[tid];
    int s = (int)(v >> 8) - 128;
    int bin = s - 9;
    bool qual = (bin >= T);
    int wv = tid >> 6, lane = tid & 63;
    if (qual) atomicAdd(&wcnt[wv][bin], 1);
    __syncthreads();
    int myeq = 0;
    {
        unsigned long long low = (1ull << lane) - 1ull;
        for (int vb = T; vb < NBIN; ++vb){
            unsigned long long bal = __ballot(qual && bin == vb);
            if (!bal) continue;
            if (qual && bin == vb) myeq = __popcll(bal & low);
        }
    }
    if (!qual) return;
    int cross = 0;
    for (int w2 = 0; w2 < wv; ++w2) cross += wcnt[w2][bin];
    int rank = gt[b*128 + bin] + chist[((size_t)(b*NCHUNK) + ci)*NBIN + bin] + cross + myeq;
    if (rank < PREK){
        int n = ci*256 + tid;               // == ((h*128+w)*8 + a)
        int a = n & 7, wc = (n >> 3) & 127;
        const int* p = data + (((size_t)(b*96 + a*12)) << 14) + (h << 7) + wc;
        int d0 = p[0], d1 = p[1 << 14], d2 = p[2 << 14], d3 = p[3 << 14];
        float4 an = ((const float4*)anchors)[n];
        float cx = __fmul_rn(__fadd_rn(an.x, an.z), 0.5f);
        float cy = __fmul_rn(__fadd_rn(an.y, an.w), 0.5f);
        float wx = __fsub_rn(an.z, an.x), wy = __fsub_rn(an.w, an.y);
        float dx = __fmul_rn((float)d0, 0.0625f), dy = __fmul_rn((float)d1, 0.0625f);
        float ex = __fmul_rn((float)etab[d2 + 128], 0.0625f);
        float ey = __fmul_rn((float)etab[d3 + 128], 0.0625f);
        float pcx = __fadd_rn(cx, __fmul_rn(dx, wx));
        float pcy = __fadd_rn(cy, __fmul_rn(dy, wy));
        float hx = __fmul_rn(__fmul_rn(wx, ex), 0.5f);
        float hy = __fmul_rn(__fmul_rn(wy, ey), 0.5f);
        float x1 = clampb(__fsub_rn(pcx, hx)), y1 = clampb(__fsub_rn(pcy, hy));
        float x2 = clampb(__fadd_rn(pcx, hx)), y2 = clampb(__fadd_rn(pcy, hy));
        dbox[b*PREK + rank] = make_float4(x1, y1, x2, y2);
        dmeta[b*PREK + rank] = (int)v;
    }
}

// K45: per batch (1024 thr): stable per-class partition into LDS, bitmask-matrix NMS
//      (one wave per class), ballot compaction to the 300 outputs
__global__ void __launch_bounds__(1024) k45_nms_out(const float4* __restrict__ dbox,
                                                    const int* __restrict__ dmeta,
                                                    float* __restrict__ out){
    int b = blockIdx.x, tid = threadIdx.x, lane = tid & 63, wv = tid >> 6;
    __shared__ float X1[1024], Y1[1024], X2[1024], Y2[1024], AR[1024];
    __shared__ unsigned long long MAT[1024][4];
    __shared__ unsigned char KEEP[1024];
    __shared__ int wq[16][8];
    __shared__ int cbs[8], ccn[8];
    __shared__ int wcn[16];
    __shared__ int totS;

    // phase 1: read rank-ordered decoded boxes, stable per-class partition
    int v = dmeta[b*PREK + tid];
    float4 bb = dbox[b*PREK + tid];
    bool valid = (v >= 0);
    int lc = valid ? (v & 255) : -1;
    float sval = valid ? __fmul_rn((float)((v >> 8) - 128), 0.0625f) : 0.0f;
    int win = 0;
#pragma unroll
    for (int c = 0; c < 8; ++c){
        unsigned long long bal = __ballot(lc == c);
        if (lane == 0) wq[wv][c] = __popcll(bal);
        if (lc == c) win = __popcll(bal & ((1ull << lane) - 1ull));
    }
    __syncthreads();
    if (tid < 8){
        int run = 0;
        for (int w2 = 0; w2 < 16; ++w2){ int t = wq[w2][tid]; wq[w2][tid] = run; run += t; }
        ccn[tid] = run;
    }
    __syncthreads();
    if (tid == 0){
        int run = 0;
        for (int c = 0; c < 8; ++c){ cbs[c] = run; run += ccn[c]; }
    }
    __syncthreads();
    int p = 0;
    if (valid){
        p = cbs[lc] + wq[wv][lc] + win;
        float off = (float)(lc << 12);
        float ox1 = __fadd_rn(bb.x, off), oy1 = __fadd_rn(bb.y, off);
        float ox2 = __fadd_rn(bb.z, off), oy2 = __fadd_rn(bb.w, off);
        X1[p] = ox1; Y1[p] = oy1; X2[p] = ox2; Y2[p] = oy2;
        AR[p] = __fmul_rn(__fsub_rn(ox2, ox1), __fsub_rn(oy2, oy1));
    }
    __syncthreads();

    // phase 2: NMS, one wave per class (waves 8..15 idle to the barrier)
    if (wv < 8){
        int M = ccn[wv], base = cbs[wv];
        if (M > 0){
            if (M <= 256){
                // cache column boxes in registers (static slots)
                float cx1[4], cy1[4], cx2[4], cy2[4], ca[4];
#pragma unroll
                for (int g = 0; g < 4; ++g){
                    int j = g*64 + lane;
                    int ad = base + ((j < M) ? j : 0);
                    cx1[g]=X1[ad]; cy1[g]=Y1[ad]; cx2[g]=X2[ad]; cy2[g]=Y2[ad]; ca[g]=AR[ad];
                }
                // build bit matrix: row i, word g = ballot(IoU(i,j)>thr && j>i)
                for (int i = 0; i < M; ++i){
                    float xi1 = X1[base+i], yi1 = Y1[base+i];
                    float xi2 = X2[base+i], yi2 = Y2[base+i], ai = AR[base+i];
#pragma unroll
                    for (int g = 0; g < 4; ++g){
                        if (g*64 < M){
                            unsigned long long bal = 0;
                            if ((g+1)*64 > i){      // word may contain j > i
                                bool o = false;
                                int j = g*64 + lane;
                                if (j < M && j > i){
                                    float wx = fmaxf(__fsub_rn(fminf(xi2, cx2[g]), fmaxf(xi1, cx1[g])), 0.0f);
                                    float wy = fmaxf(__fsub_rn(fminf(yi2, cy2[g]), fmaxf(yi1, cy1[g])), 0.0f);
                                    float inter = __fmul_rn(wx, wy);
                                    float den = __fadd_rn(__fsub_rn(__fadd_rn(ai, ca[g]), inter), 1e-9f);
                                    o = (__fdiv_rn(inter, den) > 0.5f);
                                }
                                bal = __ballot(o);
                            }
                            if (lane == 0) MAT[base+i][g] = bal;
                        }
                    }
                }
                // serial walk: OR alive rows into removed mask (rows prefetched)
                unsigned long long rem0=0, rem1=0, rem2=0, rem3=0;
                unsigned long long c0 = MAT[base][0], c1 = MAT[base][1];
                unsigned long long c2 = MAT[base][2], c3 = MAT[base][3];
                for (int i = 0; i < M; ++i){
                    unsigned long long r0=c0, r1=c1, r2=c2, r3=c3;
                    int inx = (i+1 < M) ? i+1 : i;
                    c0 = MAT[base+inx][0]; c1 = MAT[base+inx][1];
                    c2 = MAT[base+inx][2]; c3 = MAT[base+inx][3];
                    int s = i >> 6;
                    unsigned long long rs = (s==0) ? rem0 : (s==1) ? rem1 : (s==2) ? rem2 : rem3;
                    if (!((rs >> (i & 63)) & 1ull)){
                        rem0 |= r0; rem1 |= r1; rem2 |= r2; rem3 |= r3;
                    }
                }
                {
                    int j0 = lane;
                    if (j0       < M) KEEP[base+j0]       = (unsigned char)(((rem0 >> lane) & 1ull) ^ 1ull);
                    if (j0 + 64  < M) KEEP[base+j0+64]    = (unsigned char)(((rem1 >> lane) & 1ull) ^ 1ull);
                    if (j0 + 128 < M) KEEP[base+j0+128]   = (unsigned char)(((rem2 >> lane) & 1ull) ^ 1ull);
                    if (j0 + 192 < M) KEEP[base+j0+192]   = (unsigned char)(((rem3 >> lane) & 1ull) ^ 1ull);
                }
            } else {
                // fallback (class > 256 boxes): wave-serial greedy in LDS
                for (int m = lane; m < M; m += 64) KEEP[base+m] = 0;   // 1 = suppressed
                for (int i = 0; i < M; ++i){
                    if (KEEP[base+i]) continue;
                    float xi1 = X1[base+i], yi1 = Y1[base+i];
                    float xi2 = X2[base+i], yi2 = Y2[base+i], ai = AR[base+i];
                    for (int j = i + 1 + lane; j < M; j += 64){
                        if (KEEP[base+j]) continue;
                        float wx = fmaxf(__fsub_rn(fminf(xi2, X2[base+j]), fmaxf(xi1, X1[base+j])), 0.0f);
                        float wy = fmaxf(__fsub_rn(fminf(yi2, Y2[base+j]), fmaxf(yi1, Y1[base+j])), 0.0f);
                        float inter = __fmul_rn(wx, wy);
                        float den = __fadd_rn(__fsub_rn(__fadd_rn(ai, AR[base+j]), inter), 1e-9f);
                        if (__fdiv_rn(inter, den) > 0.5f) KEEP[base+j] = 1;
                    }
                }
                for (int m = lane; m < M; m += 64) KEEP[base+m] ^= 1;  // -> 1 = keep
            }
        }
    }
    __syncthreads();

    // phase 3: rank-ordered compaction to first 300
    bool kp = valid && (KEEP[p] != 0);
    unsigned long long bal = __ballot(kp);
    if (lane == 0) wcn[wv] = __popcll(bal);
    __syncthreads();
    if (tid == 0){
        int r = 0;
        for (int w2 = 0; w2 < 16; ++w2){ int t = wcn[w2]; wcn[w2] = r; r += t; }
        totS = r;
    }
    __syncthreads();
    int pos = wcn[wv] + __popcll(bal & ((1ull << lane) - 1ull));
    float* boxes  = out;
    float* scores = out + Bb*POSTK*4;
    float* labs   = out + Bb*POSTK*5;
    if (kp && pos < POSTK){
        int o = (b*POSTK + pos)*4;
        boxes[o+0] = bb.x; boxes[o+1] = bb.y; boxes[o+2] = bb.z; boxes[o+3] = bb.w;
        scores[b*POSTK + pos] = sval;
        labs[b*POSTK + pos] = (float)lc;
    }
    int tot = totS < POSTK ? totS : POSTK;
    if (tid >= tot && tid < POSTK){
        int o = (b*POSTK + tid)*4;
        boxes[o+0] = 0.f; boxes[o+1] = 0.f; boxes[o+2] = 0.f; boxes[o+3] = 0.f;
        scores[b*POSTK + tid] = 0.f;
        labs[b*POSTK + tid] = -1.0f;
    }
}

extern "C" void kernel_launch(void* const* d_in, const int* in_sizes, int n_in,
                              void* d_out, int out_size, void* d_ws, size_t ws_size,
                              hipStream_t stream) {
    const int*   data    = (const int*)d_in[0];
    const float* anchors = (const float*)d_in[1];
    const int*   etab    = (const int*)d_in[2];
    float* out = (float*)d_out;

    char* ws = (char*)d_ws;
    size_t off = 0;
    auto alloc = [&](size_t bytes)->char*{ char* p = ws + off; off += (bytes + 255) & ~(size_t)255; return p; };
    unsigned short* sc16 = (unsigned short*)alloc((size_t)Bb*8*16384*2);   // 2 MB
    int* chist           = (int*)alloc((size_t)Bb*NCHUNK*NBIN*4);          // 1.9 MB
    int* gt              = (int*)alloc((size_t)Bb*128*4);
    int* Tb_             = (int*)alloc((size_t)Bb*4);
    float4* dbox         = (float4*)alloc((size_t)Bb*PREK*16);             // 128 KB
    int* dmeta           = (int*)alloc((size_t)Bb*PREK*4);                 // 32 KB
    (void)ws_size; (void)in_sizes; (void)n_in; (void)out_size;

    k1_scores<<<Bb*128, 256, 0, stream>>>(data, sc16, chist);
    k2_select<<<Bb, 256, 0, stream>>>(chist, gt, Tb_, dmeta);
    k3_rank<<<Bb*NCHUNK, 256, 0, stream>>>(sc16, chist, gt, Tb_, data, anchors, etab, dbox, dmeta);
    k45_nms_out<<<Bb, 1024, 0, stream>>>(dbox, dmeta, out);
}

// Round 7
// 153.282 us; speedup vs baseline: 1.8754x; 1.1632x over previous
//
#include <hip/hip_runtime.h>
#include <stdint.h>

#define Bb 8
#define PREK 1024
#define POSTK 300
#define NBIN 120            // scores 9..127 -> bin = s-9
#define NCHUNK 512          // 256-candidate chunks per batch

__device__ __forceinline__ float clampb(float v){ return fminf(fmaxf(v, 0.0f), 1024.0f); }

// K1: best score + first-argmax per anchor (int4 vectorized), packed u16 [(s+128)<<8|lab]
//     layout sc16[b][a][h*128+w]; per-32w-chunk histogram -> chist[(b*512+ci)*120+bin]
__global__ void __launch_bounds__(256) k1_scores(const int* __restrict__ data,
                                                 unsigned short* __restrict__ sc16,
                                                 int* __restrict__ chist){
    int blk = blockIdx.x;                 // 8*128: (b, h)
    int b = blk >> 7, h = blk & 127;
    int tid = threadIdx.x;
    int a = tid >> 5, wg = tid & 31;
    int w = wg << 2;
    const int* p = data + (((size_t)(b*96 + a*12 + 4)) << 14) + (h << 7) + w;
    int4 m = *(const int4*)p;
    int4 lb = make_int4(0,0,0,0);
#pragma unroll
    for (int c = 1; c < 8; ++c){
        int4 v = *(const int4*)(p + ((size_t)c << 14));
        if (v.x > m.x){ m.x = v.x; lb.x = c; }
        if (v.y > m.y){ m.y = v.y; lb.y = c; }
        if (v.z > m.z){ m.z = v.z; lb.z = c; }
        if (v.w > m.w){ m.w = v.w; lb.w = c; }
    }
    ushort4 st;
    st.x = (unsigned short)(((m.x + 128) << 8) | lb.x);
    st.y = (unsigned short)(((m.y + 128) << 8) | lb.y);
    st.z = (unsigned short)(((m.z + 128) << 8) | lb.z);
    st.w = (unsigned short)(((m.w + 128) << 8) | lb.w);
    *(ushort4*)(sc16 + (((size_t)(b*8 + a)) << 14) + (h << 7) + w) = st;

    __shared__ int hist[4][NBIN];
    for (int i = tid; i < 4*NBIN; i += 256) ((int*)hist)[i] = 0;
    __syncthreads();
    int q = wg >> 3;
    if (m.x >= 9) atomicAdd(&hist[q][m.x-9], 1);
    if (m.y >= 9) atomicAdd(&hist[q][m.y-9], 1);
    if (m.z >= 9) atomicAdd(&hist[q][m.z-9], 1);
    if (m.w >= 9) atomicAdd(&hist[q][m.w-9], 1);
    __syncthreads();
    int* cb = chist + ((size_t)(b*NCHUNK + h*4)) * NBIN;
    for (int i = tid; i < 4*NBIN; i += 256) cb[i] = ((int*)hist)[i];
}

// K2: per batch: column-sum global hist (coalesced, no atomics), suffix -> gt/T,
//     init dmeta, then exclusive chunk-scan for bins >= T
__global__ void __launch_bounds__(256) k2_select(int* __restrict__ chist, int* __restrict__ gt,
                                                 int* __restrict__ Tb_, int* __restrict__ dmeta){
    int b = blockIdx.x, tid = threadIdx.x;
    __shared__ int hs2[2][NBIN];
    __shared__ int suf[128];
    __shared__ int Tsh;
    __shared__ int sb[512];
    if (tid == 0) Tsh = -1;
    int half = tid >> 7, bin = tid & 127;
    const int* cb = chist + (size_t)b * NCHUNK * NBIN;
    if (bin < NBIN){
        int s = 0;
        const int* p2 = cb + (size_t)half*256*NBIN + bin;
#pragma unroll 8
        for (int ch = 0; ch < 256; ++ch) s += p2[(size_t)ch * NBIN];
        hs2[half][bin] = s;
    }
    __syncthreads();
    int hbin = 0;
    if (tid < 128){
        hbin = (tid < NBIN) ? hs2[0][tid] + hs2[1][tid] : 0;
        suf[tid] = hbin;
    }
    __syncthreads();
    for (int off = 1; off < 128; off <<= 1){
        int v = 0;
        if (tid < 128 && tid + off < 128) v = suf[tid + off];
        __syncthreads();
        if (tid < 128) suf[tid] += v;
        __syncthreads();
    }
    if (tid < NBIN){
        gt[b*128 + tid] = suf[tid] - hbin;
        if (suf[tid] >= PREK) atomicMax(&Tsh, tid);
    }
    __syncthreads();
    int T = Tsh > 0 ? Tsh : 0;
    if (tid == 0) Tb_[b] = T;
    for (int k = tid; k < PREK; k += 256) dmeta[b*PREK + k] = -1;
    int i0 = tid, i1 = tid + 256;
    for (int abin = T; abin < NBIN; ++abin){
        int* basep = chist + (size_t)(b*NCHUNK) * NBIN + abin;
        int v0 = basep[(size_t)i0 * NBIN], v1 = basep[(size_t)i1 * NBIN];
        sb[i0] = v0; sb[i1] = v1;
        __syncthreads();
        for (int off = 1; off < 512; off <<= 1){
            int a0 = (i0 >= off) ? sb[i0 - off] : 0;
            int a1 = (i1 >= off) ? sb[i1 - off] : 0;
            __syncthreads();
            sb[i0] += a0; sb[i1] += a1;
            __syncthreads();
        }
        basep[(size_t)i0 * NBIN] = sb[i0] - v0;
        basep[(size_t)i1 * NBIN] = sb[i1] - v1;
        __syncthreads();
    }
}

// K3: stable rank via ballots + cross-wave hist; ranked candidates decode their box
//     bit-exact and scatter dbox/dmeta by rank
__global__ void __launch_bounds__(256) k3_rank(const unsigned short* __restrict__ sc16,
                                               const int* __restrict__ chist,
                                               const int* __restrict__ gt, const int* __restrict__ Tb_,
                                               const int* __restrict__ data,
                                               const float* __restrict__ anchors,
                                               const int* __restrict__ etab,
                                               float4* __restrict__ dbox, int* __restrict__ dmeta){
    int blk = blockIdx.x;                // 8*512: (b, ci)
    int b = blk >> 9, ci = blk & 511;
    int tid = threadIdx.x;
    int h = ci >> 2, w0 = (ci & 3) << 5;
    __shared__ unsigned short sc[256];
    __shared__ int wcnt[4][NBIN];
    if (tid < 64){
        int a = tid & 7, wq = tid >> 3;
        ushort4 v4 = *(const ushort4*)(sc16 + (((size_t)(b*8 + a)) << 14) + (h << 7) + w0 + (wq << 2));
        sc[(wq*4 + 0)*8 + a] = v4.x;
        sc[(wq*4 + 1)*8 + a] = v4.y;
        sc[(wq*4 + 2)*8 + a] = v4.z;
        sc[(wq*4 + 3)*8 + a] = v4.w;
    }
    for (int i = tid; i < 4*NBIN; i += 256) ((int*)wcnt)[i] = 0;
    int T = Tb_[b];
    __syncthreads();
    unsigned short v = sc[tid];
    int s = (int)(v >> 8) - 128;
    int bin = s - 9;
    bool qual = (bin >= T);
    int wv = tid >> 6, lane = tid & 63;
    if (qual) atomicAdd(&wcnt[wv][bin], 1);
    __syncthreads();
    int myeq = 0;
    {
        unsigned long long low = (1ull << lane) - 1ull;
        for (int vb = T; vb < NBIN; ++vb){
            unsigned long long bal = __ballot(qual && bin == vb);
            if (!bal) continue;
            if (qual && bin == vb) myeq = __popcll(bal & low);
        }
    }
    if (!qual) return;
    int cross = 0;
    for (int w2 = 0; w2 < wv; ++w2) cross += wcnt[w2][bin];
    int rank = gt[b*128 + bin] + chist[((size_t)(b*NCHUNK) + ci)*NBIN + bin] + cross + myeq;
    if (rank < PREK){
        int n = ci*256 + tid;               // == ((h*128+w)*8 + a)
        int a = n & 7, wc = (n >> 3) & 127;
        const int* p = data + (((size_t)(b*96 + a*12)) << 14) + (h << 7) + wc;
        int d0 = p[0], d1 = p[1 << 14], d2 = p[2 << 14], d3 = p[3 << 14];
        float4 an = ((const float4*)anchors)[n];
        float cx = __fmul_rn(__fadd_rn(an.x, an.z), 0.5f);
        float cy = __fmul_rn(__fadd_rn(an.y, an.w), 0.5f);
        float wx = __fsub_rn(an.z, an.x), wy = __fsub_rn(an.w, an.y);
        float dx = __fmul_rn((float)d0, 0.0625f), dy = __fmul_rn((float)d1, 0.0625f);
        float ex = __fmul_rn((float)etab[d2 + 128], 0.0625f);
        float ey = __fmul_rn((float)etab[d3 + 128], 0.0625f);
        float pcx = __fadd_rn(cx, __fmul_rn(dx, wx));
        float pcy = __fadd_rn(cy, __fmul_rn(dy, wy));
        float hx = __fmul_rn(__fmul_rn(wx, ex), 0.5f);
        float hy = __fmul_rn(__fmul_rn(wy, ey), 0.5f);
        float x1 = clampb(__fsub_rn(pcx, hx)), y1 = clampb(__fsub_rn(pcy, hy));
        float x2 = clampb(__fadd_rn(pcx, hx)), y2 = clampb(__fadd_rn(pcy, hy));
        dbox[b*PREK + rank] = make_float4(x1, y1, x2, y2);
        dmeta[b*PREK + rank] = (int)v;
    }
}

// K45: per batch (1024 thr): stable per-class partition into LDS, register-resident
//      row-mask NMS (one wave per class, no ballots), ballot compaction to 300 outputs
__global__ void __launch_bounds__(1024) k45_nms_out(const float4* __restrict__ dbox,
                                                    const int* __restrict__ dmeta,
                                                    float* __restrict__ out){
    int b = blockIdx.x, tid = threadIdx.x, lane = tid & 63, wv = tid >> 6;
    __shared__ float X1[1024], Y1[1024], X2[1024], Y2[1024], AR[1024];
    __shared__ unsigned char KEEP[1024];
    __shared__ int wq[16][8];
    __shared__ int cbs[8], ccn[8];
    __shared__ int wcn[16];
    __shared__ int totS;

    // phase 1: read rank-ordered decoded boxes, stable per-class partition
    int v = dmeta[b*PREK + tid];
    float4 bb = dbox[b*PREK + tid];
    bool valid = (v >= 0);
    int lc = valid ? (v & 255) : -1;
    float sval = valid ? __fmul_rn((float)((v >> 8) - 128), 0.0625f) : 0.0f;
    KEEP[tid] = 0;
    int win = 0;
#pragma unroll
    for (int c = 0; c < 8; ++c){
        unsigned long long bal = __ballot(lc == c);
        if (lane == 0) wq[wv][c] = __popcll(bal);
        if (lc == c) win = __popcll(bal & ((1ull << lane) - 1ull));
    }
    __syncthreads();
    if (tid < 8){
        int run = 0;
        for (int w2 = 0; w2 < 16; ++w2){ int t = wq[w2][tid]; wq[w2][tid] = run; run += t; }
        ccn[tid] = run;
    }
    __syncthreads();
    if (tid == 0){
        int run = 0;
        for (int c = 0; c < 8; ++c){ cbs[c] = run; run += ccn[c]; }
    }
    __syncthreads();
    int p = 0;
    if (valid){
        p = cbs[lc] + wq[wv][lc] + win;
        float off = (float)(lc << 12);
        float ox1 = __fadd_rn(bb.x, off), oy1 = __fadd_rn(bb.y, off);
        float ox2 = __fadd_rn(bb.z, off), oy2 = __fadd_rn(bb.w, off);
        X1[p] = ox1; Y1[p] = oy1; X2[p] = ox2; Y2[p] = oy2;
        AR[p] = __fmul_rn(__fsub_rn(ox2, ox1), __fsub_rn(oy2, oy1));
    }
    __syncthreads();

    // phase 2: NMS, one wave per class (waves 8..15 idle to the barrier)
    if (wv < 8){
        int M = ccn[wv], base = cbs[wv];
        if (M > 0 && M <= 256){
            // lane owns rows lane, lane+64, lane+128, lane+192
            float rx1[4], ry1[4], rx2[4], ry2[4], rar[4];
#pragma unroll
            for (int g = 0; g < 4; ++g){
                int r = g*64 + lane;
                int ad = base + ((r < M) ? r : 0);
                rx1[g]=X1[ad]; ry1[g]=Y1[ad]; rx2[g]=X2[ad]; ry2[g]=Y2[ad]; rar[g]=AR[ad];
            }
            unsigned long long mk[4][4];   // [row-group][col-word], all static-indexed
#pragma unroll
            for (int g = 0; g < 4; ++g)
#pragma unroll
                for (int w2 = 0; w2 < 4; ++w2) mk[g][w2] = 0ull;

            // build: loop columns j (wave-uniform LDS broadcast), per-lane bit sets
#pragma unroll
            for (int jw = 0; jw < 4; ++jw){
                if (jw*64 < M){
                    int lim = M - jw*64; if (lim > 64) lim = 64;
                    for (int jl = 0; jl < lim; ++jl){
                        int j = jw*64 + jl;
                        int aj = base + j;
                        float jx1 = X1[aj], jy1 = Y1[aj], jx2 = X2[aj], jy2 = Y2[aj], jar = AR[aj];
#pragma unroll
                        for (int g = 0; g < 4; ++g){
                            if (g*64 < M){
                                int i = g*64 + lane;
                                float wx = fmaxf(__fsub_rn(fminf(rx2[g], jx2), fmaxf(rx1[g], jx1)), 0.0f);
                                float wy = fmaxf(__fsub_rn(fminf(ry2[g], jy2), fmaxf(ry1[g], jy1)), 0.0f);
                                float inter = __fmul_rn(wx, wy);
                                float den = __fadd_rn(__fsub_rn(__fadd_rn(rar[g], jar), inter), 1e-9f);
                                bool o = (__fdiv_rn(inter, den) > 0.5f) && (j > i);
                                mk[g][jw] |= o ? (1ull << jl) : 0ull;
                            }
                        }
                    }
                }
            }

            // walk: replicated removed-mask in registers; alive rows broadcast via shfl
            unsigned long long r0=0ull, r1=0ull, r2=0ull, r3=0ull;
#pragma unroll
            for (int iw = 0; iw < 4; ++iw){
                if (iw*64 < M){
                    int lim = M - iw*64; if (lim > 64) lim = 64;
                    for (int il = 0; il < lim; ++il){
                        unsigned long long cur = (iw==0)?r0:(iw==1)?r1:(iw==2)?r2:r3;
                        if (!((cur >> il) & 1ull)){          // wave-uniform (replicated)
                            unsigned long long w0 = __shfl(mk[iw][0], il);
                            unsigned long long w1 = __shfl(mk[iw][1], il);
                            unsigned long long w2_ = __shfl(mk[iw][2], il);
                            unsigned long long w3_ = __shfl(mk[iw][3], il);
                            r0 |= w0; r1 |= w1; r2 |= w2_; r3 |= w3_;
                        }
                    }
                }
            }
#pragma unroll
            for (int g = 0; g < 4; ++g){
                int r = g*64 + lane;
                unsigned long long rg = (g==0)?r0:(g==1)?r1:(g==2)?r2:r3;
                if (r < M) KEEP[base + r] = (unsigned char)(((rg >> lane) & 1ull) ^ 1ull);
            }
        } else if (M > 256){
            // fallback: wave-serial greedy in LDS
            for (int m = lane; m < M; m += 64) KEEP[base+m] = 0;   // 1 = suppressed
            for (int i = 0; i < M; ++i){
                if (KEEP[base+i]) continue;
                float xi1 = X1[base+i], yi1 = Y1[base+i];
                float xi2 = X2[base+i], yi2 = Y2[base+i], ai = AR[base+i];
                for (int j = i + 1 + lane; j < M; j += 64){
                    if (KEEP[base+j]) continue;
                    float wx = fmaxf(__fsub_rn(fminf(xi2, X2[base+j]), fmaxf(xi1, X1[base+j])), 0.0f);
                    float wy = fmaxf(__fsub_rn(fminf(yi2, Y2[base+j]), fmaxf(yi1, Y1[base+j])), 0.0f);
                    float inter = __fmul_rn(wx, wy);
                    float den = __fadd_rn(__fsub_rn(__fadd_rn(ai, AR[base+j]), inter), 1e-9f);
                    if (__fdiv_rn(inter, den) > 0.5f) KEEP[base+j] = 1;
                }
            }
            for (int m = lane; m < M; m += 64) KEEP[base+m] ^= 1;  // -> 1 = keep
        }
    }
    __syncthreads();

    // phase 3: rank-ordered compaction to first 300
    bool kp = valid && (KEEP[p] != 0);
    unsigned long long bal = __ballot(kp);
    if (lane == 0) wcn[wv] = __popcll(bal);
    __syncthreads();
    if (tid == 0){
        int r = 0;
        for (int w2 = 0; w2 < 16; ++w2){ int t = wcn[w2]; wcn[w2] = r; r += t; }
        totS = r;
    }
    __syncthreads();
    int pos = wcn[wv] + __popcll(bal & ((1ull << lane) - 1ull));
    float* boxes  = out;
    float* scores = out + Bb*POSTK*4;
    float* labs   = out + Bb*POSTK*5;
    if (kp && pos < POSTK){
        int o = (b*POSTK + pos)*4;
        boxes[o+0] = bb.x; boxes[o+1] = bb.y; boxes[o+2] = bb.z; boxes[o+3] = bb.w;
        scores[b*POSTK + pos] = sval;
        labs[b*POSTK + pos] = (float)lc;
    }
    int tot = totS < POSTK ? totS : POSTK;
    if (tid >= tot && tid < POSTK){
        int o = (b*POSTK + tid)*4;
        boxes[o+0] = 0.f; boxes[o+1] = 0.f; boxes[o+2] = 0.f; boxes[o+3] = 0.f;
        scores[b*POSTK + tid] = 0.f;
        labs[b*POSTK + tid] = -1.0f;
    }
}

extern "C" void kernel_launch(void* const* d_in, const int* in_sizes, int n_in,
                              void* d_out, int out_size, void* d_ws, size_t ws_size,
                              hipStream_t stream) {
    const int*   data    = (const int*)d_in[0];
    const float* anchors = (const float*)d_in[1];
    const int*   etab    = (const int*)d_in[2];
    float* out = (float*)d_out;

    char* ws = (char*)d_ws;
    size_t off = 0;
    auto alloc = [&](size_t bytes)->char*{ char* p = ws + off; off += (bytes + 255) & ~(size_t)255; return p; };
    unsigned short* sc16 = (unsigned short*)alloc((size_t)Bb*8*16384*2);   // 2 MB
    int* chist           = (int*)alloc((size_t)Bb*NCHUNK*NBIN*4);          // 1.9 MB
    int* gt              = (int*)alloc((size_t)Bb*128*4);
    int* Tb_             = (int*)alloc((size_t)Bb*4);
    float4* dbox         = (float4*)alloc((size_t)Bb*PREK*16);             // 128 KB
    int* dmeta           = (int*)alloc((size_t)Bb*PREK*4);                 // 32 KB
    (void)ws_size; (void)in_sizes; (void)n_in; (void)out_size;

    k1_scores<<<Bb*128, 256, 0, stream>>>(data, sc16, chist);
    k2_select<<<Bb, 256, 0, stream>>>(chist, gt, Tb_, dmeta);
    k3_rank<<<Bb*NCHUNK, 256, 0, stream>>>(sc16, chist, gt, Tb_, data, anchors, etab, dbox, dmeta);
    k45_nms_out<<<Bb, 1024, 0, stream>>>(dbox, dmeta, out);
}